// Round 7
// baseline (209.926 us; speedup 1.0000x reference)
//
#include <hip/hip_runtime.h>

// out[i,v] = sum_j exp(-g*max(xn_i + yn_j - 2 x_i.y_j, 0)) * b[j,v]
// N=M=16384, D=32, Dv=16, fp32.
//
// Round 7: occupancy play. Single staged record buffer (no double-buffer):
// LDS 12800 (SB) + 9216 (P) = 22016 B -> 7 blocks/CU (28 waves, vs 4 blocks
// /34.8KB at r6). JSPLIT 16->32 (grid 2048) so 7+ blocks are actually
// resident. Cross-block TLP hides the per-tile stage wait and the per-f
// MFMA->exp2->LDS-round-trip latency chains that pinned r4-r6 at ~130us
// (Occupancy 33%, all pipes <55% busy).
// Record per 64-j tile: [yn' 256B | yh 64x80B | yl 64x80B | bTh 16x144B] = 12800 B.

#define NPTS 16384
#define D    32
#define DV   16
#define IBLK 256
#define JSPLIT 32
#define JBLK 64
#define NTILE  (NPTS / JBLK)        // 256
#define TILES  (NTILE / JSPLIT)     // 8 per block
#define REC    12800
#define YH_OFF 256
#define YL_OFF 5376
#define BT_OFF 10496
#define PTS    72                   // P row stride in halves

typedef _Float16 half8   __attribute__((ext_vector_type(8)));
typedef _Float16 half4_t __attribute__((ext_vector_type(4)));
typedef __fp16   cvt2_t  __attribute__((ext_vector_type(2)));
typedef float    float4_t __attribute__((ext_vector_type(4)));
typedef unsigned int u32;

__device__ __forceinline__ void async16(const void* g, void* l) {
  __builtin_amdgcn_global_load_lds((const __attribute__((address_space(1))) u32*)g,
                                   (__attribute__((address_space(3))) u32*)l, 16, 0, 0);
}

__device__ __forceinline__ void stage_tile(const char* __restrict__ g,
                                           char* __restrict__ l, int tid) {
  async16(g + tid * 16,         l + tid * 16);
  async16(g + 4096 + tid * 16,  l + 4096 + tid * 16);
  async16(g + 8192 + tid * 16,  l + 8192 + tid * 16);
  if (tid < 32) async16(g + 12288 + tid * 16, l + 12288 + tid * 16);
}

// ---------------- prologue: records (yn' scaled, yh, yl, bTh) + out zero ----
__global__ __launch_bounds__(256) void rbf_prologue(
    const float* __restrict__ ls, const float* __restrict__ y,
    const float* __restrict__ b, char* __restrict__ rec0,
    float* __restrict__ outz) {
  __shared__ _Float16 sbt[256][17];
  const int tid = threadIdx.x;
  const int j = blockIdx.x * 256 + tid;
  const int tt = j >> 6, jloc = j & 63;
  char* rec = rec0 + (size_t)tt * REC;
  const float nl2g = -ls[0] * 1.4426950408889634f;

  // y row: scaled yn' + plain hi/lo split
  const float4* yp = (const float4*)(y + (size_t)j * D);
  float s = 0.f;
  _Float16 hi[32], lo[32];
  #pragma unroll
  for (int c = 0; c < 8; ++c) {
    float4 v = yp[c];
    float f[4] = {v.x, v.y, v.z, v.w};
    #pragma unroll
    for (int k = 0; k < 4; ++k) {
      s = fmaf(f[k], f[k], s);
      _Float16 h = (_Float16)f[k];
      hi[c*4+k] = h;
      lo[c*4+k] = (_Float16)(f[k] - (float)h);
    }
  }
  ((float*)rec)[jloc] = nl2g * s;
  #pragma unroll
  for (int c = 0; c < 4; ++c) {
    *(half8*)(rec + YH_OFF + jloc * 80 + c * 16) = *(half8*)&hi[c*8];
    *(half8*)(rec + YL_OFF + jloc * 80 + c * 16) = *(half8*)&lo[c*8];
  }

  // b: LDS transpose -> bTh[v][jloc] rows (stride 72 halves)
  const float4* bp = (const float4*)(b + (size_t)j * DV);
  #pragma unroll
  for (int c = 0; c < 4; ++c) {
    float4 v = bp[c];
    sbt[tid][c*4+0] = (_Float16)v.x; sbt[tid][c*4+1] = (_Float16)v.y;
    sbt[tid][c*4+2] = (_Float16)v.z; sbt[tid][c*4+3] = (_Float16)v.w;
  }
  __syncthreads();
  #pragma unroll
  for (int r = 0; r < 2; ++r) {
    int cch = r * 256 + tid;                 // 512 chunks of 16B (4 tiles/block)
    int t4 = cch >> 7, rem = cch & 127, v = rem >> 3, jg = rem & 7;
    _Float16 tmp[8];
    #pragma unroll
    for (int k = 0; k < 8; ++k) tmp[k] = sbt[t4*64 + jg*8 + k][v];
    *(half8*)(rec0 + (size_t)(blockIdx.x*4 + t4)*REC + BT_OFF + v*144 + jg*16) =
        *(half8*)tmp;
  }

  // zero d_out (fused memset): 64 blocks x 256 threads x 4 float4 = 1 MB
  float4 z = {0.f, 0.f, 0.f, 0.f};
  float4* ozp = (float4*)outz;
  #pragma unroll
  for (int r = 0; r < 4; ++r) ozp[blockIdx.x * 1024 + r * 256 + tid] = z;
}

// ---------------- main MFMA kernel ----------------
__global__ __launch_bounds__(256) void rbf_mfma(
    const float* __restrict__ ls, const float* __restrict__ x,
    const char* __restrict__ rec0, float* __restrict__ out) {
  __shared__ __align__(16) char SB[REC];               // 12800 B (single buffer)
  __shared__ __align__(16) _Float16 P[4][16 * PTS];    // 9216 B

  const int tid  = threadIdx.x;
  const int lane = tid & 63, w = tid >> 6;
  const int t = lane & 15, q = lane >> 4;
  const int iblk = blockIdx.x & 63, jseg = blockIdx.x >> 6;   // jseg 0..31
  const int tseg = jseg * TILES;

  const float nl2g = -ls[0] * 1.4426950408889634f;
  const float m2g  = -2.0f * nl2g;            // positive; xs = m2g * x

  // x fragments (4 per wave): xs = (-2*nl2g)*x split hi/lo; xn' = nl2g*xn+14
  half8 xh[4], xl[4];
  float xns[4];
  #pragma unroll
  for (int f = 0; f < 4; ++f) {
    const int row = iblk * IBLK + f * 64 + w * 16 + t;
    const float4* xp = (const float4*)(x + (size_t)row * D + q * 8);
    float4 a0 = xp[0], a1 = xp[1];
    float fv[8] = {a0.x,a0.y,a0.z,a0.w,a1.x,a1.y,a1.z,a1.w};
    float s = 0.f;
    #pragma unroll
    for (int k = 0; k < 8; ++k) {
      s = fmaf(fv[k], fv[k], s);
      float vv = m2g * fv[k];
      _Float16 h = (_Float16)vv;
      xh[f][k] = h;
      xl[f][k] = (_Float16)(vv - (float)h);
    }
    s += __shfl_xor(s, 16);
    s += __shfl_xor(s, 32);
    xns[f] = fmaf(nl2g, s, 14.0f);
  }

  float4_t acc[4] = {{0,0,0,0},{0,0,0,0},{0,0,0,0},{0,0,0,0}};
  _Float16* __restrict__ myP = &P[w][0];

  for (int k = 0; k < TILES; ++k) {
    stage_tile(rec0 + (size_t)(tseg + k) * REC, &SB[0], tid);
    __syncthreads();     // drains staging vmcnt; all waves see the record

    const float* ynp = (const float*)&SB[0];
    const char* yhp = &SB[0] + YH_OFF;
    const char* ylp = &SB[0] + YL_OFF;
    const _Float16* btp = (const _Float16*)(&SB[0] + BT_OFF);

    // per-tile y fragments, yn' vec, bT rows: read once, reuse over 4 frags
    half8 ah[4], al[4];
    float4_t yn4[4];
    #pragma unroll
    for (int s = 0; s < 4; ++s) {
      ah[s]  = *(const half8*)(yhp + (s * 16 + t) * 80 + q * 16);
      al[s]  = *(const half8*)(ylp + (s * 16 + t) * 80 + q * 16);
      yn4[s] = *(const float4_t*)(ynp + s * 16 + q * 4);
    }
    const half8 bh0 = *(const half8*)(btp + t * PTS + q * 8);
    const half8 bh1 = *(const half8*)(btp + t * PTS + 32 + q * 8);

    #pragma unroll
    for (int f = 0; f < 4; ++f) {
      #pragma unroll
      for (int s = 0; s < 4; ++s) {
        // c = nl2g*(xn+yn) + 14 + nl2g*(-2 x.y)  (3-MFMA hi/lo split)
        float4_t c = {yn4[s][0] + xns[f], yn4[s][1] + xns[f],
                      yn4[s][2] + xns[f], yn4[s][3] + xns[f]};
        c = __builtin_amdgcn_mfma_f32_16x16x32_f16(ah[s], xh[f], c, 0, 0, 0);
        c = __builtin_amdgcn_mfma_f32_16x16x32_f16(ah[s], xl[f], c, 0, 0, 0);
        c = __builtin_amdgcn_mfma_f32_16x16x32_f16(al[s], xh[f], c, 0, 0, 0);
        union { half4_t h4; cvt2_t c2[2]; } u;
        u.c2[0] = __builtin_amdgcn_cvt_pkrtz(exp2f(c[0]), exp2f(c[1]));
        u.c2[1] = __builtin_amdgcn_cvt_pkrtz(exp2f(c[2]), exp2f(c[3]));
        *(half4_t*)&myP[t * PTS + s * 16 + q * 4] = u.h4;
      }
      // Same-wave P write->read: ordered by MayAlias + in-order DS pipe.
      const half8 pt0 = *(const half8*)&myP[t * PTS + q * 8];
      const half8 pt1 = *(const half8*)&myP[t * PTS + 32 + q * 8];
      acc[f] = __builtin_amdgcn_mfma_f32_16x16x32_f16(bh0, pt0, acc[f], 0, 0, 0);
      acc[f] = __builtin_amdgcn_mfma_f32_16x16x32_f16(bh1, pt1, acc[f], 0, 0, 0);
    }
    __syncthreads();     // all waves done reading SB before restaging
  }

  const float sc = 0.00006103515625f;  // 2^-14
  #pragma unroll
  for (int f = 0; f < 4; ++f) {
    float* orow = out + (size_t)(iblk * IBLK + f * 64 + w * 16 + t) * DV + q * 4;
    #pragma unroll
    for (int r = 0; r < 4; ++r) atomicAdd(&orow[r], acc[f][r] * sc);
  }
}

// ---------------- fallback (round-0 fp32 kernel, no ws) ----------------
#define BJ     128
#define BLOCK  256
#define FJSPLIT 32
#define SYP    36

__global__ __launch_bounds__(BLOCK) void rbf_fp32_kernel(
    const float* __restrict__ ls, const float* __restrict__ x,
    const float* __restrict__ y, const float* __restrict__ b,
    float* __restrict__ out, int N, int M) {
  __shared__ float sy[BJ * SYP];
  __shared__ float sb[BJ * DV];
  __shared__ float syn[BJ];
  const int itiles = N / BLOCK;
  const int itile  = blockIdx.x & (itiles - 1);
  const int jseg   = blockIdx.x / itiles;
  const int i      = itile * BLOCK + threadIdx.x;
  const int jlen   = M / FJSPLIT;
  const int j0     = jseg * jlen;
  const float g    = ls[0];
  const float nl2g = -g * 1.4426950408889634f;
  float xr[D]; float xn = 0.f;
  {
    const float4* xp = (const float4*)(x + (size_t)i * D);
    #pragma unroll
    for (int qq = 0; qq < D / 4; ++qq) {
      float4 v = xp[qq];
      xr[4*qq+0]=v.x; xr[4*qq+1]=v.y; xr[4*qq+2]=v.z; xr[4*qq+3]=v.w;
      xn += v.x*v.x + v.y*v.y + v.z*v.z + v.w*v.w;
    }
  }
  float acc[DV];
  #pragma unroll
  for (int v = 0; v < DV; ++v) acc[v] = 0.f;
  for (int jt = j0; jt < j0 + jlen; jt += BJ) {
    {
      const float4* src = (const float4*)(y + (size_t)jt * D);
      #pragma unroll
      for (int r = 0; r < (BJ * D / 4) / BLOCK; ++r) {
        int e4 = r * BLOCK + threadIdx.x;
        int j  = e4 >> 3; int dq = e4 & 7;
        *(float4*)&sy[j * SYP + dq * 4] = src[e4];
      }
      const float4* bsrc = (const float4*)(b + (size_t)jt * DV);
      #pragma unroll
      for (int r = 0; r < (BJ * DV / 4) / BLOCK; ++r) {
        int e4 = r * BLOCK + threadIdx.x;
        *(float4*)&sb[e4 * 4] = bsrc[e4];
      }
    }
    __syncthreads();
    if (threadIdx.x < BJ) {
      const float* row = &sy[threadIdx.x * SYP];
      float s0=0,s1=0,s2=0,s3=0;
      #pragma unroll
      for (int d = 0; d < D; d += 4) {
        s0=fmaf(row[d+0],row[d+0],s0); s1=fmaf(row[d+1],row[d+1],s1);
        s2=fmaf(row[d+2],row[d+2],s2); s3=fmaf(row[d+3],row[d+3],s3);
      }
      syn[threadIdx.x] = (s0+s1)+(s2+s3);
    }
    __syncthreads();
    #pragma unroll 2
    for (int j = 0; j < BJ; ++j) {
      const float* yrow = &sy[j * SYP];
      float d0=0,d1=0,d2=0,d3=0;
      #pragma unroll
      for (int d = 0; d < D; d += 4) {
        d0=fmaf(xr[d+0],yrow[d+0],d0); d1=fmaf(xr[d+1],yrow[d+1],d1);
        d2=fmaf(xr[d+2],yrow[d+2],d2); d3=fmaf(xr[d+3],yrow[d+3],d3);
      }
      float dot=(d0+d1)+(d2+d3);
      float sq = fmaxf(xn + syn[j] - 2.0f*dot, 0.0f);
      float p  = exp2f(nl2g * sq);
      const float* brow = &sb[j * DV];
      #pragma unroll
      for (int v = 0; v < DV; ++v) acc[v] = fmaf(p, brow[v], acc[v]);
    }
    __syncthreads();
  }
  float* orow = out + (size_t)i * DV;
  #pragma unroll
  for (int v = 0; v < DV; ++v) atomicAdd(&orow[v], acc[v]);
}

extern "C" void kernel_launch(void* const* d_in, const int* in_sizes, int n_in,
                              void* d_out, int out_size, void* d_ws, size_t ws_size,
                              hipStream_t stream) {
  const float* ls = (const float*)d_in[0];
  const float* x  = (const float*)d_in[1];
  const float* y  = (const float*)d_in[2];
  const float* b  = (const float*)d_in[3];
  float* out = (float*)d_out;

  const size_t need = (size_t)NTILE * REC;   // 3,276,800 B

  if (ws_size >= need) {
    char* rec0 = (char*)d_ws;
    rbf_prologue<<<NPTS / 256, 256, 0, stream>>>(ls, y, b, rec0, out);
    dim3 grid((NPTS / IBLK) * JSPLIT);       // 64 * 32 = 2048
    rbf_mfma<<<grid, 256, 0, stream>>>(ls, x, rec0, out);
  } else {
    (void)hipMemsetAsync(d_out, 0, (size_t)out_size * sizeof(float), stream);
    dim3 grid((NPTS / BLOCK) * FJSPLIT);
    rbf_fp32_kernel<<<grid, BLOCK, 0, stream>>>(ls, x, y, b, out, NPTS, NPTS);
  }
}

// Round 8
// 172.606 us; speedup vs baseline: 1.2162x; 1.2162x over previous
//
#include <hip/hip_runtime.h>

// out[i,v] = sum_j exp(-g*max(xn_i + yn_j - 2 x_i.y_j, 0)) * b[j,v]
// N=M=16384, D=32, Dv=16, fp32.
//
// Round 8: r6 structure (double-buffered staging, JSPLIT=16) with:
//  (a) __builtin_amdgcn_exp2f -> raw v_exp_f32 (arg bounded in [-210,14],
//      where HW exp2 is exact) instead of libm exp2f's ~10-15-instr OCML
//      sequence: r4-r7's VALUBusy ~52% was ~900 exp2-fixup VALU instrs
//      per wave-tile (measured 1250 vs ~300 source-level count);
//  (b) S-chain split depth 3 -> 2: c=init+ah*xh  ||  d=ah*xl -> +al*xh,
//      epilogue adds c+d (4 extra v_add per subtile, freed VALU pays it).
// Record per 64-j tile: [yn' 256B | yh 64x80B | yl 64x80B | bTh 16x144B] = 12800 B.

#define NPTS 16384
#define D    32
#define DV   16
#define IBLK 256
#define JSPLIT 16
#define JBLK 64
#define NTILE  (NPTS / JBLK)        // 256
#define TILES  (NTILE / JSPLIT)     // 16 per block
#define REC    12800
#define YH_OFF 256
#define YL_OFF 5376
#define BT_OFF 10496
#define PTS    72                   // P row stride in halves

typedef _Float16 half8   __attribute__((ext_vector_type(8)));
typedef _Float16 half4_t __attribute__((ext_vector_type(4)));
typedef __fp16   cvt2_t  __attribute__((ext_vector_type(2)));
typedef float    float4_t __attribute__((ext_vector_type(4)));
typedef unsigned int u32;

__device__ __forceinline__ void async16(const void* g, void* l) {
  __builtin_amdgcn_global_load_lds((const __attribute__((address_space(1))) u32*)g,
                                   (__attribute__((address_space(3))) u32*)l, 16, 0, 0);
}

__device__ __forceinline__ void stage_tile(const char* __restrict__ g,
                                           char* __restrict__ l, int tid) {
  async16(g + tid * 16,         l + tid * 16);
  async16(g + 4096 + tid * 16,  l + 4096 + tid * 16);
  async16(g + 8192 + tid * 16,  l + 8192 + tid * 16);
  if (tid < 32) async16(g + 12288 + tid * 16, l + 12288 + tid * 16);
}

// ---------------- prologue: records (yn' scaled, yh, yl, bTh) + out zero ----
__global__ __launch_bounds__(256) void rbf_prologue(
    const float* __restrict__ ls, const float* __restrict__ y,
    const float* __restrict__ b, char* __restrict__ rec0,
    float* __restrict__ outz) {
  __shared__ _Float16 sbt[256][17];
  const int tid = threadIdx.x;
  const int j = blockIdx.x * 256 + tid;
  const int tt = j >> 6, jloc = j & 63;
  char* rec = rec0 + (size_t)tt * REC;
  const float nl2g = -ls[0] * 1.4426950408889634f;

  // y row: scaled yn' + plain hi/lo split
  const float4* yp = (const float4*)(y + (size_t)j * D);
  float s = 0.f;
  _Float16 hi[32], lo[32];
  #pragma unroll
  for (int c = 0; c < 8; ++c) {
    float4 v = yp[c];
    float f[4] = {v.x, v.y, v.z, v.w};
    #pragma unroll
    for (int k = 0; k < 4; ++k) {
      s = fmaf(f[k], f[k], s);
      _Float16 h = (_Float16)f[k];
      hi[c*4+k] = h;
      lo[c*4+k] = (_Float16)(f[k] - (float)h);
    }
  }
  ((float*)rec)[jloc] = nl2g * s;
  #pragma unroll
  for (int c = 0; c < 4; ++c) {
    *(half8*)(rec + YH_OFF + jloc * 80 + c * 16) = *(half8*)&hi[c*8];
    *(half8*)(rec + YL_OFF + jloc * 80 + c * 16) = *(half8*)&lo[c*8];
  }

  // b: LDS transpose -> bTh[v][jloc] rows (stride 72 halves)
  const float4* bp = (const float4*)(b + (size_t)j * DV);
  #pragma unroll
  for (int c = 0; c < 4; ++c) {
    float4 v = bp[c];
    sbt[tid][c*4+0] = (_Float16)v.x; sbt[tid][c*4+1] = (_Float16)v.y;
    sbt[tid][c*4+2] = (_Float16)v.z; sbt[tid][c*4+3] = (_Float16)v.w;
  }
  __syncthreads();
  #pragma unroll
  for (int r = 0; r < 2; ++r) {
    int cch = r * 256 + tid;                 // 512 chunks of 16B (4 tiles/block)
    int t4 = cch >> 7, rem = cch & 127, v = rem >> 3, jg = rem & 7;
    _Float16 tmp[8];
    #pragma unroll
    for (int k = 0; k < 8; ++k) tmp[k] = sbt[t4*64 + jg*8 + k][v];
    *(half8*)(rec0 + (size_t)(blockIdx.x*4 + t4)*REC + BT_OFF + v*144 + jg*16) =
        *(half8*)tmp;
  }

  // zero d_out (fused memset): 64 blocks x 256 threads x 4 float4 = 1 MB
  float4 z = {0.f, 0.f, 0.f, 0.f};
  float4* ozp = (float4*)outz;
  #pragma unroll
  for (int r = 0; r < 4; ++r) ozp[blockIdx.x * 1024 + r * 256 + tid] = z;
}

// ---------------- main MFMA kernel ----------------
__global__ __launch_bounds__(256) void rbf_mfma(
    const float* __restrict__ ls, const float* __restrict__ x,
    const char* __restrict__ rec0, float* __restrict__ out) {
  __shared__ __align__(16) char SB[2][REC];            // 25600 B
  __shared__ __align__(16) _Float16 P[4][16 * PTS];    // 9216 B

  const int tid  = threadIdx.x;
  const int lane = tid & 63, w = tid >> 6;
  const int t = lane & 15, q = lane >> 4;
  const int iblk = blockIdx.x & 63, jseg = blockIdx.x >> 6;
  const int tseg = jseg * TILES;

  const float nl2g = -ls[0] * 1.4426950408889634f;
  const float m2g  = -2.0f * nl2g;            // positive; xs = m2g * x

  // x fragments (4 per wave): xs = (-2*nl2g)*x split hi/lo; xn' = nl2g*xn+14
  half8 xh[4], xl[4];
  float xns[4];
  #pragma unroll
  for (int f = 0; f < 4; ++f) {
    const int row = iblk * IBLK + f * 64 + w * 16 + t;
    const float4* xp = (const float4*)(x + (size_t)row * D + q * 8);
    float4 a0 = xp[0], a1 = xp[1];
    float fv[8] = {a0.x,a0.y,a0.z,a0.w,a1.x,a1.y,a1.z,a1.w};
    float s = 0.f;
    #pragma unroll
    for (int k = 0; k < 8; ++k) {
      s = fmaf(fv[k], fv[k], s);
      float vv = m2g * fv[k];
      _Float16 h = (_Float16)vv;
      xh[f][k] = h;
      xl[f][k] = (_Float16)(vv - (float)h);
    }
    s += __shfl_xor(s, 16);
    s += __shfl_xor(s, 32);
    xns[f] = fmaf(nl2g, s, 14.0f);
  }

  float4_t acc[4] = {{0,0,0,0},{0,0,0,0},{0,0,0,0},{0,0,0,0}};
  _Float16* __restrict__ myP = &P[w][0];

  stage_tile(rec0 + (size_t)tseg * REC, &SB[0][0], tid);
  __syncthreads();

  for (int k = 0; k < TILES; ++k) {
    if (k + 1 < TILES)
      stage_tile(rec0 + (size_t)(tseg + k + 1) * REC, &SB[(k + 1) & 1][0], tid);

    const char* rec = &SB[k & 1][0];
    const float* ynp = (const float*)rec;
    const char* yhp = rec + YH_OFF;
    const char* ylp = rec + YL_OFF;
    const _Float16* btp = (const _Float16*)(rec + BT_OFF);

    // per-tile y fragments, yn' vec, bT rows: read once, reuse over 4 frags
    half8 ah[4], al[4];
    float4_t yn4[4];
    #pragma unroll
    for (int s = 0; s < 4; ++s) {
      ah[s]  = *(const half8*)(yhp + (s * 16 + t) * 80 + q * 16);
      al[s]  = *(const half8*)(ylp + (s * 16 + t) * 80 + q * 16);
      yn4[s] = *(const float4_t*)(ynp + s * 16 + q * 4);
    }
    const half8 bh0 = *(const half8*)(btp + t * PTS + q * 8);
    const half8 bh1 = *(const half8*)(btp + t * PTS + 32 + q * 8);

    #pragma unroll
    for (int f = 0; f < 4; ++f) {
      #pragma unroll
      for (int s = 0; s < 4; ++s) {
        // c+d = nl2g*(xn+yn) + 14 + nl2g*(-2 x.y), two depth-2 MFMA chains
        float4_t c = {yn4[s][0] + xns[f], yn4[s][1] + xns[f],
                      yn4[s][2] + xns[f], yn4[s][3] + xns[f]};
        float4_t d = {0.f, 0.f, 0.f, 0.f};
        c = __builtin_amdgcn_mfma_f32_16x16x32_f16(ah[s], xh[f], c, 0, 0, 0);
        d = __builtin_amdgcn_mfma_f32_16x16x32_f16(ah[s], xl[f], d, 0, 0, 0);
        d = __builtin_amdgcn_mfma_f32_16x16x32_f16(al[s], xh[f], d, 0, 0, 0);
        // raw v_exp_f32: exact for args in [-210, 14]
        float p0 = __builtin_amdgcn_exp2f(c[0] + d[0]);
        float p1 = __builtin_amdgcn_exp2f(c[1] + d[1]);
        float p2 = __builtin_amdgcn_exp2f(c[2] + d[2]);
        float p3 = __builtin_amdgcn_exp2f(c[3] + d[3]);
        union { half4_t h4; cvt2_t c2[2]; } u;
        u.c2[0] = __builtin_amdgcn_cvt_pkrtz(p0, p1);
        u.c2[1] = __builtin_amdgcn_cvt_pkrtz(p2, p3);
        *(half4_t*)&myP[t * PTS + s * 16 + q * 4] = u.h4;
      }
      // Same-wave P write->read: ordered by MayAlias + in-order DS pipe.
      const half8 pt0 = *(const half8*)&myP[t * PTS + q * 8];
      const half8 pt1 = *(const half8*)&myP[t * PTS + 32 + q * 8];
      acc[f] = __builtin_amdgcn_mfma_f32_16x16x32_f16(bh0, pt0, acc[f], 0, 0, 0);
      acc[f] = __builtin_amdgcn_mfma_f32_16x16x32_f16(bh1, pt1, acc[f], 0, 0, 0);
    }
    __syncthreads();   // drains staging vmcnt; protects SB double buffer
  }

  const float sc = 0.00006103515625f;  // 2^-14
  #pragma unroll
  for (int f = 0; f < 4; ++f) {
    float* orow = out + (size_t)(iblk * IBLK + f * 64 + w * 16 + t) * DV + q * 4;
    #pragma unroll
    for (int r = 0; r < 4; ++r) atomicAdd(&orow[r], acc[f][r] * sc);
  }
}

// ---------------- fallback (round-0 fp32 kernel, no ws) ----------------
#define BJ     128
#define BLOCK  256
#define FJSPLIT 32
#define SYP    36

__global__ __launch_bounds__(BLOCK) void rbf_fp32_kernel(
    const float* __restrict__ ls, const float* __restrict__ x,
    const float* __restrict__ y, const float* __restrict__ b,
    float* __restrict__ out, int N, int M) {
  __shared__ float sy[BJ * SYP];
  __shared__ float sb[BJ * DV];
  __shared__ float syn[BJ];
  const int itiles = N / BLOCK;
  const int itile  = blockIdx.x & (itiles - 1);
  const int jseg   = blockIdx.x / itiles;
  const int i      = itile * BLOCK + threadIdx.x;
  const int jlen   = M / FJSPLIT;
  const int j0     = jseg * jlen;
  const float g    = ls[0];
  const float nl2g = -g * 1.4426950408889634f;
  float xr[D]; float xn = 0.f;
  {
    const float4* xp = (const float4*)(x + (size_t)i * D);
    #pragma unroll
    for (int qq = 0; qq < D / 4; ++qq) {
      float4 v = xp[qq];
      xr[4*qq+0]=v.x; xr[4*qq+1]=v.y; xr[4*qq+2]=v.z; xr[4*qq+3]=v.w;
      xn += v.x*v.x + v.y*v.y + v.z*v.z + v.w*v.w;
    }
  }
  float acc[DV];
  #pragma unroll
  for (int v = 0; v < DV; ++v) acc[v] = 0.f;
  for (int jt = j0; jt < j0 + jlen; jt += BJ) {
    {
      const float4* src = (const float4*)(y + (size_t)jt * D);
      #pragma unroll
      for (int r = 0; r < (BJ * D / 4) / BLOCK; ++r) {
        int e4 = r * BLOCK + threadIdx.x;
        int j  = e4 >> 3; int dq = e4 & 7;
        *(float4*)&sy[j * SYP + dq * 4] = src[e4];
      }
      const float4* bsrc = (const float4*)(b + (size_t)jt * DV);
      #pragma unroll
      for (int r = 0; r < (BJ * DV / 4) / BLOCK; ++r) {
        int e4 = r * BLOCK + threadIdx.x;
        *(float4*)&sb[e4 * 4] = bsrc[e4];
      }
    }
    __syncthreads();
    if (threadIdx.x < BJ) {
      const float* row = &sy[threadIdx.x * SYP];
      float s0=0,s1=0,s2=0,s3=0;
      #pragma unroll
      for (int d = 0; d < D; d += 4) {
        s0=fmaf(row[d+0],row[d+0],s0); s1=fmaf(row[d+1],row[d+1],s1);
        s2=fmaf(row[d+2],row[d+2],s2); s3=fmaf(row[d+3],row[d+3],s3);
      }
      syn[threadIdx.x] = (s0+s1)+(s2+s3);
    }
    __syncthreads();
    #pragma unroll 2
    for (int j = 0; j < BJ; ++j) {
      const float* yrow = &sy[j * SYP];
      float d0=0,d1=0,d2=0,d3=0;
      #pragma unroll
      for (int d = 0; d < D; d += 4) {
        d0=fmaf(xr[d+0],yrow[d+0],d0); d1=fmaf(xr[d+1],yrow[d+1],d1);
        d2=fmaf(xr[d+2],yrow[d+2],d2); d3=fmaf(xr[d+3],yrow[d+3],d3);
      }
      float dot=(d0+d1)+(d2+d3);
      float sq = fmaxf(xn + syn[j] - 2.0f*dot, 0.0f);
      float p  = exp2f(nl2g * sq);
      const float* brow = &sb[j * DV];
      #pragma unroll
      for (int v = 0; v < DV; ++v) acc[v] = fmaf(p, brow[v], acc[v]);
    }
    __syncthreads();
  }
  float* orow = out + (size_t)i * DV;
  #pragma unroll
  for (int v = 0; v < DV; ++v) atomicAdd(&orow[v], acc[v]);
}

extern "C" void kernel_launch(void* const* d_in, const int* in_sizes, int n_in,
                              void* d_out, int out_size, void* d_ws, size_t ws_size,
                              hipStream_t stream) {
  const float* ls = (const float*)d_in[0];
  const float* x  = (const float*)d_in[1];
  const float* y  = (const float*)d_in[2];
  const float* b  = (const float*)d_in[3];
  float* out = (float*)d_out;

  const size_t need = (size_t)NTILE * REC;   // 3,276,800 B

  if (ws_size >= need) {
    char* rec0 = (char*)d_ws;
    rbf_prologue<<<NPTS / 256, 256, 0, stream>>>(ls, y, b, rec0, out);
    dim3 grid((NPTS / IBLK) * JSPLIT);       // 64 * 16 = 1024
    rbf_mfma<<<grid, 256, 0, stream>>>(ls, x, rec0, out);
  } else {
    (void)hipMemsetAsync(d_out, 0, (size_t)out_size * sizeof(float), stream);
    dim3 grid((NPTS / BLOCK) * FJSPLIT);
    rbf_fp32_kernel<<<grid, BLOCK, 0, stream>>>(ls, x, y, b, out, NPTS, NPTS);
  }
}